// Round 10
// baseline (1545.062 us; speedup 1.0000x reference)
//
#include <hip/hip_runtime.h>
#include <hip/hip_bf16.h>
#include <hip/hip_cooperative_groups.h>

namespace cg = cooperative_groups;

#define NN 100000
#define NE 1600000
#define NQ (NE / 8)
#define CIN 64
#define HIDN 32
#define NG 128
#define SLOPE 0.01f
#define NBLK 98        // scan blocks: (NN+1023)/1024
#define MM_UNITS 12500 // NN*HIDN/256
#define AGG_UNITS 3125 // NN/32

// ---------------- fused CSR aggregation phase (grid-strided) ----------------
// hs pre-scaled by dinv. Col loads software-pipelined (proven r9 structure).

template <int FUSE>
__device__ void agg_phase(int b, int t, int gsize,
                          const __hip_bfloat16* __restrict__ hs,
                          const int* __restrict__ rowp,
                          const int* __restrict__ col,
                          const float* __restrict__ dinv,
                          const int* __restrict__ batch,
                          const float* __restrict__ cinv,
                          const float* __restrict__ bias,
                          const float* __restrict__ Wn,
                          __hip_bfloat16* __restrict__ hs_next,
                          float* __restrict__ pool,
                          float (*vrow)[32], float* sWn) {
  const int f = t & 31;
  const int sub = t >> 5;  // 0..7
  if (FUSE) {
    for (int i = t; i < HIDN * HIDN; i += 256) sWn[i] = Wn[i];
  }
  const float bf = bias[f];
  for (int u = b; u < AGG_UNITS; u += gsize) {
    __syncthreads();  // vrow reuse across units + sWn visibility
    const int base = u * 32;
    float pacc = 0.f;
    int gcur = -1;
#pragma unroll
    for (int it = 0; it < 4; ++it) {
      const int i = base + it * 8 + sub;
      float acc = __bfloat162float(hs[i * HIDN + f]);  // self-loop term
      const int rs = rowp[i];
      const int re = rowp[i + 1];
      int e = rs;
      const int nfull = (re - rs) >> 3;
      if (nfull > 0) {
        int c0 = __builtin_nontemporal_load(col + e);
        int c1 = __builtin_nontemporal_load(col + e + 1);
        int c2 = __builtin_nontemporal_load(col + e + 2);
        int c3 = __builtin_nontemporal_load(col + e + 3);
        int c4 = __builtin_nontemporal_load(col + e + 4);
        int c5 = __builtin_nontemporal_load(col + e + 5);
        int c6 = __builtin_nontemporal_load(col + e + 6);
        int c7 = __builtin_nontemporal_load(col + e + 7);
        for (int bi = 1; bi < nfull; ++bi) {
          const int n0 = __builtin_nontemporal_load(col + e + 8);
          const int n1 = __builtin_nontemporal_load(col + e + 9);
          const int n2 = __builtin_nontemporal_load(col + e + 10);
          const int n3 = __builtin_nontemporal_load(col + e + 11);
          const int n4 = __builtin_nontemporal_load(col + e + 12);
          const int n5 = __builtin_nontemporal_load(col + e + 13);
          const int n6 = __builtin_nontemporal_load(col + e + 14);
          const int n7 = __builtin_nontemporal_load(col + e + 15);
          const float v0 = __bfloat162float(hs[c0 * HIDN + f]);
          const float v1 = __bfloat162float(hs[c1 * HIDN + f]);
          const float v2 = __bfloat162float(hs[c2 * HIDN + f]);
          const float v3 = __bfloat162float(hs[c3 * HIDN + f]);
          const float v4 = __bfloat162float(hs[c4 * HIDN + f]);
          const float v5 = __bfloat162float(hs[c5 * HIDN + f]);
          const float v6 = __bfloat162float(hs[c6 * HIDN + f]);
          const float v7 = __bfloat162float(hs[c7 * HIDN + f]);
          acc += ((v0 + v1) + (v2 + v3)) + ((v4 + v5) + (v6 + v7));
          c0 = n0; c1 = n1; c2 = n2; c3 = n3; c4 = n4; c5 = n5; c6 = n6; c7 = n7;
          e += 8;
        }
        const float v0 = __bfloat162float(hs[c0 * HIDN + f]);
        const float v1 = __bfloat162float(hs[c1 * HIDN + f]);
        const float v2 = __bfloat162float(hs[c2 * HIDN + f]);
        const float v3 = __bfloat162float(hs[c3 * HIDN + f]);
        const float v4 = __bfloat162float(hs[c4 * HIDN + f]);
        const float v5 = __bfloat162float(hs[c5 * HIDN + f]);
        const float v6 = __bfloat162float(hs[c6 * HIDN + f]);
        const float v7 = __bfloat162float(hs[c7 * HIDN + f]);
        acc += ((v0 + v1) + (v2 + v3)) + ((v4 + v5) + (v6 + v7));
        e += 8;
      }
      if (re - e >= 4) {
        const int c0 = __builtin_nontemporal_load(col + e);
        const int c1 = __builtin_nontemporal_load(col + e + 1);
        const int c2 = __builtin_nontemporal_load(col + e + 2);
        const int c3 = __builtin_nontemporal_load(col + e + 3);
        const float v0 = __bfloat162float(hs[c0 * HIDN + f]);
        const float v1 = __bfloat162float(hs[c1 * HIDN + f]);
        const float v2 = __bfloat162float(hs[c2 * HIDN + f]);
        const float v3 = __bfloat162float(hs[c3 * HIDN + f]);
        acc += (v0 + v1) + (v2 + v3);
        e += 4;
      }
      for (; e < re; ++e) acc += __bfloat162float(hs[col[e] * HIDN + f]);
      float v = acc * dinv[i] + bf;
      v = v > 0.f ? v : SLOPE * v;
      if (FUSE) vrow[it * 8 + sub][f] = v;
      const int g = batch[i];
      if (g != gcur) {
        if (gcur >= 0) unsafeAtomicAdd(&pool[gcur * HIDN + f], pacc * cinv[gcur]);
        gcur = g;
        pacc = 0.f;
      }
      pacc += v;
    }
    if (gcur >= 0) unsafeAtomicAdd(&pool[gcur * HIDN + f], pacc * cinv[gcur]);

    if (FUSE) {
      __syncthreads();
#pragma unroll
      for (int q = 0; q < 4; ++q) {
        const int li = sub * 4 + q;
        const int i = base + li;
        float a = 0.f;
#pragma unroll
        for (int k = 0; k < HIDN; ++k) a += vrow[li][k] * sWn[k * HIDN + f];
        hs_next[i * HIDN + f] = __float2bfloat16(a * dinv[i]);
      }
    }
  }
}

// ---------------- the whole pipeline as one cooperative kernel ----------------

__global__ __launch_bounds__(256, 8) void k_all(
    const int* __restrict__ src, const int* __restrict__ dst,
    const int* __restrict__ batch, const float* __restrict__ x,
    const float* __restrict__ W0, const float* __restrict__ b0,
    const float* __restrict__ W1, const float* __restrict__ b1,
    const float* __restrict__ W2, const float* __restrict__ b2,
    float* __restrict__ out,
    int* __restrict__ deg, unsigned int* __restrict__ rank,
    int* __restrict__ rowp, int* __restrict__ bsum,
    float* __restrict__ dinv, float* __restrict__ cinv,
    int* __restrict__ col,
    __hip_bfloat16* __restrict__ hsA, __hip_bfloat16* __restrict__ hsB) {
  cg::grid_group gg = cg::this_grid();
  __shared__ float sWbuf[CIN * HIDN];  // 8KB; scan phases alias into it
  __shared__ float vrow[32][32];       // 4KB
  __shared__ float sWn[HIDN * HIDN];   // 4KB
  int* sscan = (int*)sWbuf;
  int* sb = (int*)sWbuf + 256;

  const int t = threadIdx.x;
  const int b = blockIdx.x;
  const int gsize = gridDim.x;
  const int gtid = b * 256 + t;
  const int gthreads = gsize * 256;

  // ---- P0: zero deg + out ----
  for (int i = gtid; i < NN; i += gthreads) deg[i] = 0;
  for (int i = gtid; i < NG * HIDN; i += gthreads) out[i] = 0.f;
  gg.sync();

  // ---- P1: atomic histogram producing u8 ranks (8 edges/thread) ----
  for (int u = gtid; u < NQ; u += gthreads) {
    int4 a = ((const int4*)dst)[2 * u];
    int4 bb = ((const int4*)dst)[2 * u + 1];
    unsigned r0 = atomicAdd(&deg[a.x], 1);
    unsigned r1 = atomicAdd(&deg[a.y], 1);
    unsigned r2 = atomicAdd(&deg[a.z], 1);
    unsigned r3 = atomicAdd(&deg[a.w], 1);
    unsigned r4 = atomicAdd(&deg[bb.x], 1);
    unsigned r5 = atomicAdd(&deg[bb.y], 1);
    unsigned r6 = atomicAdd(&deg[bb.z], 1);
    unsigned r7 = atomicAdd(&deg[bb.w], 1);
    uint2 packed;
    packed.x = r0 | (r1 << 8) | (r2 << 16) | (r3 << 24);
    packed.y = r4 | (r5 << 8) | (r6 << 16) | (r7 << 24);
    ((uint2*)rank)[u] = packed;
  }
  gg.sync();

  // ---- P2: per-block scan sums + dinv (b<NBLK); cinv (b==NBLK) ----
  int d0 = 0, d1 = 0, d2 = 0, d3 = 0, ts = 0, incl = 0;
  if (b < NBLK) {
    const int base = b * 1024 + t * 4;
    if (base < NN) { d0 = deg[base]; dinv[base] = rsqrtf((float)d0 + 1.0f); }
    if (base + 1 < NN) { d1 = deg[base + 1]; dinv[base + 1] = rsqrtf((float)d1 + 1.0f); }
    if (base + 2 < NN) { d2 = deg[base + 2]; dinv[base + 2] = rsqrtf((float)d2 + 1.0f); }
    if (base + 3 < NN) { d3 = deg[base + 3]; dinv[base + 3] = rsqrtf((float)d3 + 1.0f); }
    ts = d0 + d1 + d2 + d3;
    sscan[t] = ts;
    __syncthreads();
    for (int o = 1; o < 256; o <<= 1) {
      int v = (t >= o) ? sscan[t - o] : 0;
      __syncthreads();
      sscan[t] += v;
      __syncthreads();
    }
    incl = sscan[t];
    if (t == 255) bsum[b] = incl;
  } else if (b == NBLK) {
    if (t <= NG) {
      int lo = 0, hi = NN;  // lower_bound of t in sorted batch
      while (lo < hi) {
        int mid = (lo + hi) >> 1;
        if (batch[mid] < t) lo = mid + 1; else hi = mid;
      }
      sb[t] = lo;
    }
    __syncthreads();
    if (t < NG) {
      int c = sb[t + 1] - sb[t];
      cinv[t] = 1.0f / (3.0f * fmaxf((float)c, 1.0f));
    }
  }
  gg.sync();

  // ---- P3: rowp from bsum prefix + register-carried local scan ----
  if (b < NBLK) {
    if (t < NBLK) sscan[t] = bsum[t];
    __syncthreads();
    int off = 0;
    for (int j = 0; j < b; ++j) off += sscan[j];
    int run = off + incl - ts;
    const int base = b * 1024 + t * 4;
    if (base < NN) { rowp[base] = run; run += d0; }
    if (base + 1 < NN) { rowp[base + 1] = run; run += d1; }
    if (base + 2 < NN) { rowp[base + 2] = run; run += d2; }
    if (base + 3 < NN) { rowp[base + 3] = run; run += d3; }
    if (b == NBLK - 1 && t == 255) rowp[NN] = run;  // == NE
  }
  gg.sync();

  // ---- P4: scatter (no atomics) then mm0 ----
  for (int u = gtid; u < NQ; u += gthreads) {
    int4 da = ((const int4*)dst)[2 * u];
    int4 db = ((const int4*)dst)[2 * u + 1];
    uint2 rr = ((const uint2*)rank)[u];
    int4 sa = ((const int4*)src)[2 * u];
    int4 sbb = ((const int4*)src)[2 * u + 1];
    col[rowp[da.x] + (int)(rr.x & 0xff)] = sa.x;
    col[rowp[da.y] + (int)((rr.x >> 8) & 0xff)] = sa.y;
    col[rowp[da.z] + (int)((rr.x >> 16) & 0xff)] = sa.z;
    col[rowp[da.w] + (int)(rr.x >> 24)] = sa.w;
    col[rowp[db.x] + (int)(rr.y & 0xff)] = sbb.x;
    col[rowp[db.y] + (int)((rr.y >> 8) & 0xff)] = sbb.y;
    col[rowp[db.z] + (int)((rr.y >> 16) & 0xff)] = sbb.z;
    col[rowp[db.w] + (int)(rr.y >> 24)] = sbb.w;
  }
  __syncthreads();
  for (int i = t; i < CIN * HIDN; i += 256) sWbuf[i] = W0[i];
  __syncthreads();
  for (int g = b; g < MM_UNITS; g += gsize) {
    const int gid2 = g * 256 + t;
    const int node = gid2 >> 5;
    const int f = gid2 & 31;
    const float* xr = x + node * CIN;
    float acc = 0.f;
#pragma unroll
    for (int k = 0; k < CIN; ++k) acc += xr[k] * sWbuf[k * HIDN + f];
    hsA[node * HIDN + f] = __float2bfloat16(acc * dinv[node]);
  }
  gg.sync();

  // ---- P5/P6/P7: three GCN layers (agg + fused next mm) ----
  agg_phase<1>(b, t, gsize, hsA, rowp, col, dinv, batch, cinv, b0, W1, hsB, out, vrow, sWn);
  gg.sync();
  agg_phase<1>(b, t, gsize, hsB, rowp, col, dinv, batch, cinv, b1, W2, hsA, out, vrow, sWn);
  gg.sync();
  agg_phase<0>(b, t, gsize, hsA, rowp, col, dinv, batch, cinv, b2, nullptr, nullptr, out, vrow, sWn);
}

// ---------------- launch ----------------

extern "C" void kernel_launch(void* const* d_in, const int* in_sizes, int n_in,
                              void* d_out, int out_size, void* d_ws, size_t ws_size,
                              hipStream_t stream) {
  const float* x = (const float*)d_in[0];
  const float* W0 = (const float*)d_in[1];
  const float* b0 = (const float*)d_in[2];
  const float* W1 = (const float*)d_in[3];
  const float* b1 = (const float*)d_in[4];
  const float* W2 = (const float*)d_in[5];
  const float* b2 = (const float*)d_in[6];
  const int* src = (const int*)d_in[7];
  const int* dst = (const int*)d_in[8];
  const int* batch = (const int*)d_in[9];
  float* out = (float*)d_out;

  char* ws = (char*)d_ws;
  auto carve = [&](size_t bytes) -> char* {
    char* p = ws;
    ws += (bytes + 255) & ~(size_t)255;
    return p;
  };
  int* deg = (int*)carve(NN * 4);
  unsigned int* rank = (unsigned int*)carve((size_t)NE);  // u8 per edge
  int* rowp = (int*)carve((NN + 1) * 4);
  int* bsum = (int*)carve(128 * 4);
  float* dinv = (float*)carve(NN * 4);
  float* cinv = (float*)carve(NG * 4);
  int* col = (int*)carve((size_t)NE * 4);
  __hip_bfloat16* hsA = (__hip_bfloat16*)carve((size_t)NN * HIDN * 2);
  __hip_bfloat16* hsB = (__hip_bfloat16*)carve((size_t)NN * HIDN * 2);

  int bpc = 0;
  if (hipOccupancyMaxActiveBlocksPerMultiprocessor(&bpc, k_all, 256, 0) != hipSuccess || bpc < 1)
    bpc = 1;
  int grid = bpc * 256;
  if (grid > 2048) grid = 2048;
  if (grid < 256) grid = 256;

  void* kargs[] = {
      (void*)&src, (void*)&dst, (void*)&batch, (void*)&x,
      (void*)&W0, (void*)&b0, (void*)&W1, (void*)&b1, (void*)&W2, (void*)&b2,
      (void*)&out, (void*)&deg, (void*)&rank, (void*)&rowp, (void*)&bsum,
      (void*)&dinv, (void*)&cinv, (void*)&col, (void*)&hsA, (void*)&hsB};
  hipLaunchCooperativeKernel(k_all, dim3(grid), dim3(256), kargs, 0, stream);
}

// Round 11
// 1520.669 us; speedup vs baseline: 1.0160x; 1.0160x over previous
//
#include <hip/hip_runtime.h>
#include <hip/hip_bf16.h>

#define NN 100000
#define NE 1600000
#define NQ (NE / 8)
#define CIN 64
#define HIDN 32
#define NG 128
#define SLOPE 0.01f
#define NBLK 98        // scan blocks: (NN+1023)/1024
#define MM_UNITS 12500 // NN*HIDN/256
#define AGG_UNITS 3125 // NN/32
#define MAX_GRID 2048

// ---------------- custom grid barrier: flag-per-block + gen broadcast ----------------
// Arrival: uncontended per-block release store (no RMW pileup).
// Detect: block 0 scans flags in parallel, s_sleep-throttled.
// Wakeup: release store of gen; spinners poll RELAXED + final ACQUIRE, throttled.

__device__ __forceinline__ void gbar(unsigned* __restrict__ flags,
                                     unsigned* __restrict__ gen,
                                     unsigned mygen, int gsize, int* snot) {
  const int t = threadIdx.x;
  const int b = blockIdx.x;
  __syncthreads();
  if (b == 0) {
    if (t == 0) {
      *snot = 0;
      __hip_atomic_store(&flags[0], mygen, __ATOMIC_RELEASE, __HIP_MEMORY_SCOPE_AGENT);
    }
    __syncthreads();
    for (;;) {
      int ok = 1;
      for (int s = t; s < gsize; s += 256)
        if (__hip_atomic_load(&flags[s], __ATOMIC_ACQUIRE, __HIP_MEMORY_SCOPE_AGENT) != mygen) {
          ok = 0;
          break;
        }
      if (!ok) *snot = 1;
      __syncthreads();
      if (*snot == 0) break;
      __builtin_amdgcn_s_sleep(8);
      __syncthreads();
      if (t == 0) *snot = 0;
      __syncthreads();
    }
    if (t == 0) __hip_atomic_store(gen, mygen, __ATOMIC_RELEASE, __HIP_MEMORY_SCOPE_AGENT);
    __threadfence();
    __syncthreads();
  } else {
    if (t == 0) {
      __hip_atomic_store(&flags[b], mygen, __ATOMIC_RELEASE, __HIP_MEMORY_SCOPE_AGENT);
      while (__hip_atomic_load(gen, __ATOMIC_RELAXED, __HIP_MEMORY_SCOPE_AGENT) != mygen) {
        __builtin_amdgcn_s_sleep(15);
        __builtin_amdgcn_s_sleep(15);
        __builtin_amdgcn_s_sleep(15);
        __builtin_amdgcn_s_sleep(15);
      }
      (void)__hip_atomic_load(gen, __ATOMIC_ACQUIRE, __HIP_MEMORY_SCOPE_AGENT);
    }
    __threadfence();
    __syncthreads();
  }
}

// ---------------- fused CSR aggregation phase (grid-strided, r9-proven loop) ----------------

template <int FUSE>
__device__ void agg_phase(int b, int t, int gsize,
                          const __hip_bfloat16* __restrict__ hs,
                          const int* __restrict__ rowp,
                          const int* __restrict__ col,
                          const float* __restrict__ dinv,
                          const int* __restrict__ batch,
                          const float* __restrict__ cinv,
                          const float* __restrict__ bias,
                          const float* __restrict__ Wn,
                          __hip_bfloat16* __restrict__ hs_next,
                          float* __restrict__ pool,
                          float (*vrow)[32], float* sWn) {
  const int f = t & 31;
  const int sub = t >> 5;  // 0..7
  if (FUSE) {
    for (int i = t; i < HIDN * HIDN; i += 256) sWn[i] = Wn[i];
  }
  const float bf = bias[f];
  for (int u = b; u < AGG_UNITS; u += gsize) {
    __syncthreads();  // vrow reuse across units + sWn visibility
    const int base = u * 32;
    float pacc = 0.f;
    int gcur = -1;
#pragma unroll
    for (int it = 0; it < 4; ++it) {
      const int i = base + it * 8 + sub;
      float acc = __bfloat162float(hs[i * HIDN + f]);  // self-loop term
      const int rs = rowp[i];
      const int re = rowp[i + 1];
      int e = rs;
      const int nfull = (re - rs) >> 3;
      if (nfull > 0) {
        int c0 = __builtin_nontemporal_load(col + e);
        int c1 = __builtin_nontemporal_load(col + e + 1);
        int c2 = __builtin_nontemporal_load(col + e + 2);
        int c3 = __builtin_nontemporal_load(col + e + 3);
        int c4 = __builtin_nontemporal_load(col + e + 4);
        int c5 = __builtin_nontemporal_load(col + e + 5);
        int c6 = __builtin_nontemporal_load(col + e + 6);
        int c7 = __builtin_nontemporal_load(col + e + 7);
        for (int bi = 1; bi < nfull; ++bi) {
          const int n0 = __builtin_nontemporal_load(col + e + 8);
          const int n1 = __builtin_nontemporal_load(col + e + 9);
          const int n2 = __builtin_nontemporal_load(col + e + 10);
          const int n3 = __builtin_nontemporal_load(col + e + 11);
          const int n4 = __builtin_nontemporal_load(col + e + 12);
          const int n5 = __builtin_nontemporal_load(col + e + 13);
          const int n6 = __builtin_nontemporal_load(col + e + 14);
          const int n7 = __builtin_nontemporal_load(col + e + 15);
          const float v0 = __bfloat162float(hs[c0 * HIDN + f]);
          const float v1 = __bfloat162float(hs[c1 * HIDN + f]);
          const float v2 = __bfloat162float(hs[c2 * HIDN + f]);
          const float v3 = __bfloat162float(hs[c3 * HIDN + f]);
          const float v4 = __bfloat162float(hs[c4 * HIDN + f]);
          const float v5 = __bfloat162float(hs[c5 * HIDN + f]);
          const float v6 = __bfloat162float(hs[c6 * HIDN + f]);
          const float v7 = __bfloat162float(hs[c7 * HIDN + f]);
          acc += ((v0 + v1) + (v2 + v3)) + ((v4 + v5) + (v6 + v7));
          c0 = n0; c1 = n1; c2 = n2; c3 = n3; c4 = n4; c5 = n5; c6 = n6; c7 = n7;
          e += 8;
        }
        const float v0 = __bfloat162float(hs[c0 * HIDN + f]);
        const float v1 = __bfloat162float(hs[c1 * HIDN + f]);
        const float v2 = __bfloat162float(hs[c2 * HIDN + f]);
        const float v3 = __bfloat162float(hs[c3 * HIDN + f]);
        const float v4 = __bfloat162float(hs[c4 * HIDN + f]);
        const float v5 = __bfloat162float(hs[c5 * HIDN + f]);
        const float v6 = __bfloat162float(hs[c6 * HIDN + f]);
        const float v7 = __bfloat162float(hs[c7 * HIDN + f]);
        acc += ((v0 + v1) + (v2 + v3)) + ((v4 + v5) + (v6 + v7));
        e += 8;
      }
      if (re - e >= 4) {
        const int c0 = __builtin_nontemporal_load(col + e);
        const int c1 = __builtin_nontemporal_load(col + e + 1);
        const int c2 = __builtin_nontemporal_load(col + e + 2);
        const int c3 = __builtin_nontemporal_load(col + e + 3);
        const float v0 = __bfloat162float(hs[c0 * HIDN + f]);
        const float v1 = __bfloat162float(hs[c1 * HIDN + f]);
        const float v2 = __bfloat162float(hs[c2 * HIDN + f]);
        const float v3 = __bfloat162float(hs[c3 * HIDN + f]);
        acc += (v0 + v1) + (v2 + v3);
        e += 4;
      }
      for (; e < re; ++e) acc += __bfloat162float(hs[col[e] * HIDN + f]);
      float v = acc * dinv[i] + bf;
      v = v > 0.f ? v : SLOPE * v;
      if (FUSE) vrow[it * 8 + sub][f] = v;
      const int g = batch[i];
      if (g != gcur) {
        if (gcur >= 0) unsafeAtomicAdd(&pool[gcur * HIDN + f], pacc * cinv[gcur]);
        gcur = g;
        pacc = 0.f;
      }
      pacc += v;
    }
    if (gcur >= 0) unsafeAtomicAdd(&pool[gcur * HIDN + f], pacc * cinv[gcur]);

    if (FUSE) {
      __syncthreads();
#pragma unroll
      for (int q = 0; q < 4; ++q) {
        const int li = sub * 4 + q;
        const int i = base + li;
        float a = 0.f;
#pragma unroll
        for (int k = 0; k < HIDN; ++k) a += vrow[li][k] * sWn[k * HIDN + f];
        hs_next[i * HIDN + f] = __float2bfloat16(a * dinv[i]);
      }
    }
  }
}

// ---------------- the whole pipeline as one cooperative kernel ----------------

__global__ __launch_bounds__(256, 8) void k_all(
    const int* __restrict__ src, const int* __restrict__ dst,
    const int* __restrict__ batch, const float* __restrict__ x,
    const float* __restrict__ W0, const float* __restrict__ b0,
    const float* __restrict__ W1, const float* __restrict__ b1,
    const float* __restrict__ W2, const float* __restrict__ b2,
    float* __restrict__ out,
    unsigned* __restrict__ flags, unsigned* __restrict__ gen,
    int* __restrict__ deg, unsigned int* __restrict__ rank,
    int* __restrict__ rowp, int* __restrict__ bsum,
    float* __restrict__ dinv, float* __restrict__ cinv,
    int* __restrict__ col,
    __hip_bfloat16* __restrict__ hsA, __hip_bfloat16* __restrict__ hsB) {
  __shared__ float sWbuf[CIN * HIDN];  // 8KB; scan phases alias into it
  __shared__ float vrow[32][32];       // 4KB
  __shared__ float sWn[HIDN * HIDN];   // 4KB
  __shared__ int snot;
  int* sscan = (int*)sWbuf;
  int* sb = (int*)sWbuf + 256;

  const int t = threadIdx.x;
  const int b = blockIdx.x;
  const int gsize = gridDim.x;
  const int gtid = b * 256 + t;
  const int gthreads = gsize * 256;
  unsigned mygen = 0;

  // ---- P0: zero deg + out ----
  for (int i = gtid; i < NN; i += gthreads) deg[i] = 0;
  for (int i = gtid; i < NG * HIDN; i += gthreads) out[i] = 0.f;
  gbar(flags, gen, ++mygen, gsize, &snot);

  // ---- P1: atomic histogram producing u8 ranks (8 edges/thread) ----
  for (int u = gtid; u < NQ; u += gthreads) {
    int4 a = ((const int4*)dst)[2 * u];
    int4 bb = ((const int4*)dst)[2 * u + 1];
    unsigned r0 = atomicAdd(&deg[a.x], 1);
    unsigned r1 = atomicAdd(&deg[a.y], 1);
    unsigned r2 = atomicAdd(&deg[a.z], 1);
    unsigned r3 = atomicAdd(&deg[a.w], 1);
    unsigned r4 = atomicAdd(&deg[bb.x], 1);
    unsigned r5 = atomicAdd(&deg[bb.y], 1);
    unsigned r6 = atomicAdd(&deg[bb.z], 1);
    unsigned r7 = atomicAdd(&deg[bb.w], 1);
    uint2 packed;
    packed.x = r0 | (r1 << 8) | (r2 << 16) | (r3 << 24);
    packed.y = r4 | (r5 << 8) | (r6 << 16) | (r7 << 24);
    ((uint2*)rank)[u] = packed;
  }
  gbar(flags, gen, ++mygen, gsize, &snot);

  // ---- P2: per-block scan sums + dinv (b<NBLK); cinv (b==NBLK) ----
  int d0 = 0, d1 = 0, d2 = 0, d3 = 0, ts = 0, incl = 0;
  if (b < NBLK) {
    const int base = b * 1024 + t * 4;
    if (base < NN) { d0 = deg[base]; dinv[base] = rsqrtf((float)d0 + 1.0f); }
    if (base + 1 < NN) { d1 = deg[base + 1]; dinv[base + 1] = rsqrtf((float)d1 + 1.0f); }
    if (base + 2 < NN) { d2 = deg[base + 2]; dinv[base + 2] = rsqrtf((float)d2 + 1.0f); }
    if (base + 3 < NN) { d3 = deg[base + 3]; dinv[base + 3] = rsqrtf((float)d3 + 1.0f); }
    ts = d0 + d1 + d2 + d3;
    sscan[t] = ts;
    __syncthreads();
    for (int o = 1; o < 256; o <<= 1) {
      int v = (t >= o) ? sscan[t - o] : 0;
      __syncthreads();
      sscan[t] += v;
      __syncthreads();
    }
    incl = sscan[t];
    if (t == 255) bsum[b] = incl;
  } else if (b == NBLK) {
    if (t <= NG) {
      int lo = 0, hi = NN;  // lower_bound of t in sorted batch
      while (lo < hi) {
        int mid = (lo + hi) >> 1;
        if (batch[mid] < t) lo = mid + 1; else hi = mid;
      }
      sb[t] = lo;
    }
    __syncthreads();
    if (t < NG) {
      int c = sb[t + 1] - sb[t];
      cinv[t] = 1.0f / (3.0f * fmaxf((float)c, 1.0f));
    }
  }
  gbar(flags, gen, ++mygen, gsize, &snot);

  // ---- P3: rowp from bsum prefix + register-carried local scan ----
  if (b < NBLK) {
    if (t < NBLK) sscan[t] = bsum[t];
    __syncthreads();
    int off = 0;
    for (int j = 0; j < b; ++j) off += sscan[j];
    int run = off + incl - ts;
    const int base = b * 1024 + t * 4;
    if (base < NN) { rowp[base] = run; run += d0; }
    if (base + 1 < NN) { rowp[base + 1] = run; run += d1; }
    if (base + 2 < NN) { rowp[base + 2] = run; run += d2; }
    if (base + 3 < NN) { rowp[base + 3] = run; run += d3; }
    if (b == NBLK - 1 && t == 255) rowp[NN] = run;  // == NE
  }
  gbar(flags, gen, ++mygen, gsize, &snot);

  // ---- P4: scatter (no atomics) then mm0 ----
  for (int u = gtid; u < NQ; u += gthreads) {
    int4 da = ((const int4*)dst)[2 * u];
    int4 db = ((const int4*)dst)[2 * u + 1];
    uint2 rr = ((const uint2*)rank)[u];
    int4 sa = ((const int4*)src)[2 * u];
    int4 sbb = ((const int4*)src)[2 * u + 1];
    col[rowp[da.x] + (int)(rr.x & 0xff)] = sa.x;
    col[rowp[da.y] + (int)((rr.x >> 8) & 0xff)] = sa.y;
    col[rowp[da.z] + (int)((rr.x >> 16) & 0xff)] = sa.z;
    col[rowp[da.w] + (int)(rr.x >> 24)] = sa.w;
    col[rowp[db.x] + (int)(rr.y & 0xff)] = sbb.x;
    col[rowp[db.y] + (int)((rr.y >> 8) & 0xff)] = sbb.y;
    col[rowp[db.z] + (int)((rr.y >> 16) & 0xff)] = sbb.z;
    col[rowp[db.w] + (int)(rr.y >> 24)] = sbb.w;
  }
  __syncthreads();
  for (int i = t; i < CIN * HIDN; i += 256) sWbuf[i] = W0[i];
  __syncthreads();
  for (int g = b; g < MM_UNITS; g += gsize) {
    const int gid2 = g * 256 + t;
    const int node = gid2 >> 5;
    const int f = gid2 & 31;
    const float* xr = x + node * CIN;
    float acc = 0.f;
#pragma unroll
    for (int k = 0; k < CIN; ++k) acc += xr[k] * sWbuf[k * HIDN + f];
    hsA[node * HIDN + f] = __float2bfloat16(acc * dinv[node]);
  }
  gbar(flags, gen, ++mygen, gsize, &snot);

  // ---- P5/P6/P7: three GCN layers (agg + fused next mm) ----
  agg_phase<1>(b, t, gsize, hsA, rowp, col, dinv, batch, cinv, b0, W1, hsB, out, vrow, sWn);
  gbar(flags, gen, ++mygen, gsize, &snot);
  agg_phase<1>(b, t, gsize, hsB, rowp, col, dinv, batch, cinv, b1, W2, hsA, out, vrow, sWn);
  gbar(flags, gen, ++mygen, gsize, &snot);
  agg_phase<0>(b, t, gsize, hsA, rowp, col, dinv, batch, cinv, b2, nullptr, nullptr, out, vrow, sWn);
}

// ---------------- launch ----------------

extern "C" void kernel_launch(void* const* d_in, const int* in_sizes, int n_in,
                              void* d_out, int out_size, void* d_ws, size_t ws_size,
                              hipStream_t stream) {
  const float* x = (const float*)d_in[0];
  const float* W0 = (const float*)d_in[1];
  const float* b0 = (const float*)d_in[2];
  const float* W1 = (const float*)d_in[3];
  const float* b1 = (const float*)d_in[4];
  const float* W2 = (const float*)d_in[5];
  const float* b2 = (const float*)d_in[6];
  const int* src = (const int*)d_in[7];
  const int* dst = (const int*)d_in[8];
  const int* batch = (const int*)d_in[9];
  float* out = (float*)d_out;

  char* ws = (char*)d_ws;
  auto carve = [&](size_t bytes) -> char* {
    char* p = ws;
    ws += (bytes + 255) & ~(size_t)255;
    return p;
  };
  // barrier state + deg contiguous -> one memset zeroes all
  unsigned* flags = (unsigned*)carve(MAX_GRID * 4);  // 8192
  unsigned* gen = (unsigned*)carve(256);
  int* deg = (int*)carve(NN * 4);
  unsigned int* rank = (unsigned int*)carve((size_t)NE);  // u8 per edge
  int* rowp = (int*)carve((NN + 1) * 4);
  int* bsum = (int*)carve(128 * 4);
  float* dinv = (float*)carve(NN * 4);
  float* cinv = (float*)carve(NG * 4);
  int* col = (int*)carve((size_t)NE * 4);
  __hip_bfloat16* hsA = (__hip_bfloat16*)carve((size_t)NN * HIDN * 2);
  __hip_bfloat16* hsB = (__hip_bfloat16*)carve((size_t)NN * HIDN * 2);

  hipMemsetAsync(flags, 0, MAX_GRID * 4 + 256 + ((NN * 4 + 255) & ~(size_t)255), stream);

  int bpc = 0;
  if (hipOccupancyMaxActiveBlocksPerMultiprocessor(&bpc, k_all, 256, 0) != hipSuccess || bpc < 1)
    bpc = 1;
  int grid = bpc * 256;
  if (grid > MAX_GRID) grid = MAX_GRID;
  if (grid < 256) grid = 256;

  void* kargs[] = {
      (void*)&src, (void*)&dst, (void*)&batch, (void*)&x,
      (void*)&W0, (void*)&b0, (void*)&W1, (void*)&b1, (void*)&W2, (void*)&b2,
      (void*)&out, (void*)&flags, (void*)&gen, (void*)&deg, (void*)&rank,
      (void*)&rowp, (void*)&bsum, (void*)&dinv, (void*)&cinv, (void*)&col,
      (void*)&hsA, (void*)&hsB};
  hipLaunchCooperativeKernel(k_all, dim3(grid), dim3(256), kargs, 0, stream);
}